// Round 13
// baseline (1316.396 us; speedup 1.0000x reference)
//
#include <hip/hip_runtime.h>

#define BATCH 4096

typedef __attribute__((ext_vector_type(8))) short bf16x8;
typedef __attribute__((ext_vector_type(4))) float f32x4;

// Manual RNE float->bf16 (round half to even), matches HW/NumPy for normal finite values.
__device__ __forceinline__ unsigned short f2bf(float f) {
    union { float f; unsigned u; } v; v.f = f;
    unsigned r = v.u + 0x7fffu + ((v.u >> 16) & 1u);
    return (unsigned short)(r >> 16);
}
__device__ __forceinline__ unsigned packbf(float a, float b) {
    return (unsigned)f2bf(a) | ((unsigned)f2bf(b) << 16);
}

// 16 features for one x: o[0..3] = cos(1x..8x) pairs, o[4..7] = sin(1x..8x) pairs (bf16x2).
__device__ __forceinline__ void feats16(float x, unsigned o[8]) {
    float c1 = __cosf(x), s1 = __sinf(x);
    float cs[8], sn[8];
    cs[0] = c1; sn[0] = s1;
    #pragma unroll
    for (int k = 1; k < 8; ++k) {
        cs[k] = c1 * cs[k-1] - s1 * sn[k-1];
        sn[k] = s1 * cs[k-1] + c1 * sn[k-1];
    }
    #pragma unroll
    for (int k = 0; k < 4; ++k) {
        o[k]     = packbf(cs[2*k], cs[2*k+1]);
        o[4 + k] = packbf(sn[2*k], sn[2*k+1]);
    }
}

// Async global->LDS, 16 B per lane. LDS dest is wave-uniform base; HW adds lane*16.
__device__ __forceinline__ void gload_lds16(const void* g, void* l) {
    __builtin_amdgcn_global_load_lds(
        (__attribute__((address_space(1))) void*)(g),
        (__attribute__((address_space(3))) void*)(l), 16, 0, 0);
}

// ---------------- one-shot precompute kernels ----------------

// C [2][OUT][IN][8] f32  ->  B [OUT][IN*16] bf16, k = i*16 + d*8 + g
template <int IN, int OUT>
__global__ void conv_C(const float* __restrict__ C, unsigned short* __restrict__ B) {
    const int i = blockIdx.x * 256 + threadIdx.x;
    const int j = blockIdx.y;
    const float* c0 = C + ((size_t)j * IN + i) * 8;            // d=0 (cos) plane
    const float* c1 = c0 + (size_t)OUT * IN * 8;               // d=1 (sin) plane
    const float4 a0 = *(const float4*)c0;
    const float4 a1 = *(const float4*)(c0 + 4);
    const float4 s0 = *(const float4*)c1;
    const float4 s1 = *(const float4*)(c1 + 4);
    unsigned short* dst = B + ((size_t)j * IN + i) * 16;
    *(uint4*)dst       = make_uint4(packbf(a0.x, a0.y), packbf(a0.z, a0.w),
                                    packbf(a1.x, a1.y), packbf(a1.z, a1.w));
    *(uint4*)(dst + 8) = make_uint4(packbf(s0.x, s0.y), packbf(s0.z, s0.w),
                                    packbf(s1.x, s1.y), packbf(s1.z, s1.w));
}

// x [4096][768] f32 -> A1 [4096][768*16] bf16 (features of the input layer)
__global__ void feats_x_kernel(const float* __restrict__ x, unsigned short* __restrict__ A) {
    const size_t idx = (size_t)blockIdx.x * 256 + threadIdx.x;   // (b,i) linear
    unsigned o[8];
    feats16(x[idx], o);
    unsigned short* dst = A + idx * 16;
    *(uint4*)dst       = make_uint4(o[0], o[1], o[2], o[3]);
    *(uint4*)(dst + 8) = make_uint4(o[4], o[5], o[6], o[7]);
}

// Deterministic split-K reduce + feature epilogue, 4 (b,j) per thread (float4 path).
template <int N, int KSPLIT>
__global__ void reduce_feats(const float* __restrict__ P, const float* __restrict__ bias,
                             unsigned short* __restrict__ A) {
    const size_t idx = ((size_t)blockIdx.x * 256 + threadIdx.x) * 4;  // (b,j) linear, x4
    const int j = (int)(idx % N);                                      // N % 4 == 0
    float4 s = *(const float4*)(P + idx);
    #pragma unroll
    for (int z = 1; z < KSPLIT; ++z) {
        const float4 v = *(const float4*)(P + (size_t)z * BATCH * N + idx);
        s.x += v.x; s.y += v.y; s.z += v.z; s.w += v.w;
    }
    const float4 bv = *(const float4*)(bias + j);
    const float y[4] = { s.x + bv.x, s.y + bv.y, s.z + bv.z, s.w + bv.w };
    unsigned short* dst = A + idx * 16;
    #pragma unroll
    for (int e = 0; e < 4; ++e) {
        unsigned o[8];
        feats16(y[e], o);
        *(uint4*)(dst + e * 16)     = make_uint4(o[0], o[1], o[2], o[3]);
        *(uint4*)(dst + e * 16 + 8) = make_uint4(o[4], o[5], o[6], o[7]);
    }
}

// Deterministic split-K reduction: out[b][j] = sum_z P[z][b][j] + bias[j].
template <int N, int KSPLIT>
__global__ void reduce_out(const float* __restrict__ P, const float* __restrict__ bias,
                           float* __restrict__ out) {
    const size_t idx = ((size_t)blockIdx.x * 256 + threadIdx.x) * 4;   // float4 granule
    const int j = (int)(idx % N);                                       // N % 4 == 0
    float4 s = *(const float4*)(P + idx);
    #pragma unroll
    for (int z = 1; z < KSPLIT; ++z) {
        const float4 v = *(const float4*)(P + (size_t)z * BATCH * N + idx);
        s.x += v.x; s.y += v.y; s.z += v.z; s.w += v.w;
    }
    const float4 bv = *(const float4*)(bias + j);
    s.x += bv.x; s.y += bv.y; s.z += bv.z; s.w += bv.w;
    *(float4*)(out + idx) = s;
}

// ---------- main bf16 GEMM: 256x256 tile, 16 waves of 64x64, round-5 2-barrier schedule ----------
// v13: same 256² tile / BK=64 / dbuf-128KB-LDS / XOR swizzle as v9, but 16 LEAN waves
// (1024 threads, wave tile 64x64, acc[4][4]=64 VGPR) instead of 8 fat ones.
// Total regs ~116 < 128 -> 16 waves/CU = 4 waves/SIMD (v9: 2) -> MFMA latency + barrier
// drains hide across waves. Schedule is the round-5-proven minimal-race pattern:
//   STAGE(next tile) -> vmcnt(4) -> barrier -> reads+MFMA (compiler lgkm) -> lgkmcnt(0) -> barrier.
// Per wave per tile: 4 gloads staged, 16 ds_read_b128, 32 MFMA.
template <int K, int N, int KSPLIT>
__global__ __launch_bounds__(1024, 1)
void kan_gemm(const unsigned short* __restrict__ A,
              const unsigned short* __restrict__ B,
              float* __restrict__ P)
{
    __shared__ unsigned short As[2 * 256 * 64];   // 64 KB
    __shared__ unsigned short Bs[2 * 256 * 64];   // 64 KB

    const int tid  = threadIdx.x;
    const int lane = tid & 63;
    const int wave = tid >> 6;          // 0..15
    const int wr   = wave >> 2;         // 0..3: wave row -> 64 batch rows
    const int wc   = wave & 3;          // 0..3: wave col -> 64 out cols
    const int fr   = lane & 15;
    const int fq   = lane >> 4;

    // 2-D XCD chunk swizzle over 256-tiles (round-4 verified).
    constexpr int NBX = BATCH / 256;
    constexpr int NBY = N / 256;
    constexpr int NWG = NBX * NBY;
    constexpr int S   = NWG / 8;
    constexpr int CC  = (NBY >= 8) ? 8 : NBY;
    constexpr int CR  = S / CC;
    constexpr int GR  = NBX / CR;
    const int wg  = blockIdx.y * NBX + blockIdx.x;
    const int xc  = wg & 7;
    const int ci  = wg >> 3;
    const int row0 = ((xc % GR) * CR + ci % CR) * 256;
    const int col0 = ((xc / GR) * CC + ci / CR) * 256;

    constexpr int KCH = K / KSPLIT;
    const int kt0 = ((int)blockIdx.z * KCH) >> 6;
    const int nt  = KCH >> 6;

    // Staging: 1024 threads x 16 B = one 128-row x 64-k half per round; 2 rounds per matrix.
    const int grow = tid >> 3;                    // 0..127: row within a 128-row round
    const int scol = ((lane & 7) ^ (grow & 7)) * 16;   // pre-swizzled global 16B chunk (bytes)

    auto STA = [&](int b, int kt) {
        #pragma unroll
        for (int r = 0; r < 2; ++r)
            gload_lds16((const char*)A +
                        ((size_t)(row0 + r * 128 + grow) * K + (size_t)kt * 64) * 2 + scol,
                        (char*)&As[b * 16384 + (r * 128 + wave * 8) * 64]);
    };
    auto STB = [&](int b, int kt) {
        #pragma unroll
        for (int r = 0; r < 2; ++r)
            gload_lds16((const char*)B +
                        ((size_t)(col0 + r * 128 + grow) * K + (size_t)kt * 64) * 2 + scol,
                        (char*)&Bs[b * 16384 + (r * 128 + wave * 8) * 64]);
    };
    // Swizzled fragment reads (chunk ^= row&7; row&7 == fr&7 for all fragment rows).
    auto LDA = [&](int b, int m, int ks) -> bf16x8 {
        return *(const bf16x8*)&As[b * 16384 + (wr * 64 + m * 16 + fr) * 64 +
                                   (((ks * 4 + fq) ^ (fr & 7)) << 3)];
    };
    auto LDB = [&](int b, int n, int ks) -> bf16x8 {
        return *(const bf16x8*)&Bs[b * 16384 + (wc * 64 + n * 16 + fr) * 64 +
                                   (((ks * 4 + fq) ^ (fr & 7)) << 3)];
    };

    f32x4 acc[4][4] = {};

    // Prologue: stage tile 0 (4 gloads in flight).
    STA(0, kt0); STB(0, kt0);

    #pragma unroll 1
    for (int t = 0; t < nt; ++t) {
        const int b = t & 1;
        // Issue next tile's stages, certify current tile's 4 (oldest) retired, publish.
        if (t + 1 < nt) {
            STA(b ^ 1, kt0 + t + 1); STB(b ^ 1, kt0 + t + 1);
            asm volatile("s_waitcnt vmcnt(4)" ::: "memory");
        } else {
            asm volatile("s_waitcnt vmcnt(0)" ::: "memory");
        }
        __builtin_amdgcn_s_barrier();
        __builtin_amdgcn_sched_barrier(0);   // reads stay below the publish point

        #pragma unroll
        for (int ks = 0; ks < 2; ++ks) {
            bf16x8 aF[4], bF[4];
            #pragma unroll
            for (int m = 0; m < 4; ++m) aF[m] = LDA(b, m, ks);
            #pragma unroll
            for (int n = 0; n < 4; ++n) bF[n] = LDB(b, n, ks);
            #pragma unroll
            for (int m = 0; m < 4; ++m)
                #pragma unroll
                for (int n = 0; n < 4; ++n)
                    acc[m][n] = __builtin_amdgcn_mfma_f32_16x16x32_bf16(
                        aF[m], bF[n], acc[m][n], 0, 0, 0);
        }

        // All our ds_reads complete before any wave overwrites this buffer next iter.
        asm volatile("s_waitcnt lgkmcnt(0)" ::: "memory");
        __builtin_amdgcn_s_barrier();
    }

    // Epilogue: split-K partial plane. C/D layout: col = lane&15, row = (lane>>4)*4+reg.
    float* Pz = P + (size_t)blockIdx.z * BATCH * N;
    #pragma unroll
    for (int m = 0; m < 4; ++m) {
        const int gr0 = row0 + wr * 64 + m * 16 + fq * 4;
        #pragma unroll
        for (int n = 0; n < 4; ++n) {
            const int gc = col0 + wc * 64 + n * 16 + fr;
            #pragma unroll
            for (int q = 0; q < 4; ++q)
                Pz[(size_t)(gr0 + q) * N + gc] = acc[m][n][q];
        }
    }
}

extern "C" void kernel_launch(void* const* d_in, const int* in_sizes, int n_in,
                              void* d_out, int out_size, void* d_ws, size_t ws_size,
                              hipStream_t stream) {
    (void)in_sizes; (void)n_in; (void)ws_size; (void)out_size;
    const float* x  = (const float*)d_in[0];   // [4096][768]
    const float* C1 = (const float*)d_in[1];   // [2][2048][768][8]
    const float* b1 = (const float*)d_in[2];   // [2048]
    const float* C2 = (const float*)d_in[3];   // [2][2048][2048][8]
    const float* b2 = (const float*)d_in[4];   // [2048]
    const float* C3 = (const float*)d_in[5];   // [2][512][2048][8]
    const float* b3 = (const float*)d_in[6];   // [512]
    float* out = (float*)d_out;                // [4096][512]

    // Workspace layout, lifetime-aliased (proven). Peak 554 MB.
    char* ws = (char*)d_ws;
    const size_t SZ_A1  = (size_t)4096 * 12288 * 2;      // 100,663,296
    const size_t SZ_B1  = (size_t)2048 * 12288 * 2;      //  50,331,648
    const size_t SZ_P12 = (size_t)2 * 4096 * 2048 * 4;   //  67,108,864
    const size_t SZ_A2  = (size_t)4096 * 32768 * 2;      // 268,435,456
    unsigned short* A1 = (unsigned short*)(ws);
    unsigned short* B1 = (unsigned short*)(ws + SZ_A1);
    float*          P1 = (float*)(ws + SZ_A1 + SZ_B1);
    unsigned short* A2 = (unsigned short*)(ws + SZ_A1 + SZ_B1 + SZ_P12);
    unsigned short* B2 = (unsigned short*)(ws);                           // aliases dead A1+B1
    float*          P2 = (float*)(ws + SZ_A1 + SZ_B1 + SZ_P12 + SZ_A2);
    unsigned short* A3 = (unsigned short*)(ws);                           // aliases dead B2/P1
    unsigned short* B3 = (unsigned short*)(ws + SZ_A2);
    float*          P3 = (float*)(ws + SZ_A2 + (size_t)512 * 32768 * 2);

    // ---- layer 1: (4096 x 12288) x (2048 x 12288)^T, split-K x2 -> feats -> A2
    conv_C<768, 2048><<<dim3(768 / 256, 2048), 256, 0, stream>>>(C1, B1);
    feats_x_kernel<<<dim3((4096 * 768) / 256), 256, 0, stream>>>(x, A1);
    kan_gemm<12288, 2048, 2><<<dim3(16, 8, 2), 1024, 0, stream>>>(A1, B1, P1);
    reduce_feats<2048, 2><<<dim3((BATCH * 2048 / 4) / 256), 256, 0, stream>>>(P1, b1, A2);

    // ---- layer 2: (4096 x 32768) x (2048 x 32768)^T, split-K x2 -> feats -> A3
    conv_C<2048, 2048><<<dim3(2048 / 256, 2048), 256, 0, stream>>>(C2, B2);
    kan_gemm<32768, 2048, 2><<<dim3(16, 8, 2), 1024, 0, stream>>>(A2, B2, P2);
    reduce_feats<2048, 2><<<dim3((BATCH * 2048 / 4) / 256), 256, 0, stream>>>(P2, b2, A3);

    // ---- layer 3: (4096 x 32768) x (512 x 32768)^T, split-K x8, deterministic reduce
    conv_C<2048, 512><<<dim3(2048 / 256, 512), 256, 0, stream>>>(C3, B3);
    kan_gemm<32768, 512, 8><<<dim3(16, 2, 8), 1024, 0, stream>>>(A3, B3, P3);
    reduce_out<512, 8><<<dim3((BATCH * 512 / 4) / 256), 256, 0, stream>>>(P3, b3, out);
}

// Round 14
// 1159.052 us; speedup vs baseline: 1.1358x; 1.1358x over previous
//
#include <hip/hip_runtime.h>

#define BATCH 4096

typedef __attribute__((ext_vector_type(8))) short bf16x8;
typedef __attribute__((ext_vector_type(4))) float f32x4;

// Manual RNE float->bf16 (round half to even), matches HW/NumPy for normal finite values.
__device__ __forceinline__ unsigned short f2bf(float f) {
    union { float f; unsigned u; } v; v.f = f;
    unsigned r = v.u + 0x7fffu + ((v.u >> 16) & 1u);
    return (unsigned short)(r >> 16);
}
__device__ __forceinline__ unsigned packbf(float a, float b) {
    return (unsigned)f2bf(a) | ((unsigned)f2bf(b) << 16);
}

// 16 features for one x: o[0..3] = cos(1x..8x) pairs, o[4..7] = sin(1x..8x) pairs (bf16x2).
__device__ __forceinline__ void feats16(float x, unsigned o[8]) {
    float c1 = __cosf(x), s1 = __sinf(x);
    float cs[8], sn[8];
    cs[0] = c1; sn[0] = s1;
    #pragma unroll
    for (int k = 1; k < 8; ++k) {
        cs[k] = c1 * cs[k-1] - s1 * sn[k-1];
        sn[k] = s1 * cs[k-1] + c1 * sn[k-1];
    }
    #pragma unroll
    for (int k = 0; k < 4; ++k) {
        o[k]     = packbf(cs[2*k], cs[2*k+1]);
        o[4 + k] = packbf(sn[2*k], sn[2*k+1]);
    }
}

// Async global->LDS, 16 B per lane. LDS dest is wave-uniform base; HW adds lane*16.
__device__ __forceinline__ void gload_lds16(const void* g, void* l) {
    __builtin_amdgcn_global_load_lds(
        (__attribute__((address_space(1))) void*)(g),
        (__attribute__((address_space(3))) void*)(l), 16, 0, 0);
}

// ---------------- one-shot precompute kernels ----------------

// C [2][OUT][IN][8] f32  ->  B [OUT][IN*16] bf16, k = i*16 + d*8 + g
template <int IN, int OUT>
__global__ void conv_C(const float* __restrict__ C, unsigned short* __restrict__ B) {
    const int i = blockIdx.x * 256 + threadIdx.x;
    const int j = blockIdx.y;
    const float* c0 = C + ((size_t)j * IN + i) * 8;            // d=0 (cos) plane
    const float* c1 = c0 + (size_t)OUT * IN * 8;               // d=1 (sin) plane
    const float4 a0 = *(const float4*)c0;
    const float4 a1 = *(const float4*)(c0 + 4);
    const float4 s0 = *(const float4*)c1;
    const float4 s1 = *(const float4*)(c1 + 4);
    unsigned short* dst = B + ((size_t)j * IN + i) * 16;
    *(uint4*)dst       = make_uint4(packbf(a0.x, a0.y), packbf(a0.z, a0.w),
                                    packbf(a1.x, a1.y), packbf(a1.z, a1.w));
    *(uint4*)(dst + 8) = make_uint4(packbf(s0.x, s0.y), packbf(s0.z, s0.w),
                                    packbf(s1.x, s1.y), packbf(s1.z, s1.w));
}

// x [4096][768] f32 -> A1 [4096][768*16] bf16 (features of the input layer)
__global__ void feats_x_kernel(const float* __restrict__ x, unsigned short* __restrict__ A) {
    const size_t idx = (size_t)blockIdx.x * 256 + threadIdx.x;   // (b,i) linear
    unsigned o[8];
    feats16(x[idx], o);
    unsigned short* dst = A + idx * 16;
    *(uint4*)dst       = make_uint4(o[0], o[1], o[2], o[3]);
    *(uint4*)(dst + 8) = make_uint4(o[4], o[5], o[6], o[7]);
}

// Deterministic split-K reduce + feature epilogue, 4 (b,j) per thread (float4 path).
template <int N, int KSPLIT>
__global__ void reduce_feats(const float* __restrict__ P, const float* __restrict__ bias,
                             unsigned short* __restrict__ A) {
    const size_t idx = ((size_t)blockIdx.x * 256 + threadIdx.x) * 4;  // (b,j) linear, x4
    const int j = (int)(idx % N);                                      // N % 4 == 0
    float4 s = *(const float4*)(P + idx);
    #pragma unroll
    for (int z = 1; z < KSPLIT; ++z) {
        const float4 v = *(const float4*)(P + (size_t)z * BATCH * N + idx);
        s.x += v.x; s.y += v.y; s.z += v.z; s.w += v.w;
    }
    const float4 bv = *(const float4*)(bias + j);
    const float y[4] = { s.x + bv.x, s.y + bv.y, s.z + bv.z, s.w + bv.w };
    unsigned short* dst = A + idx * 16;
    #pragma unroll
    for (int e = 0; e < 4; ++e) {
        unsigned o[8];
        feats16(y[e], o);
        *(uint4*)(dst + e * 16)     = make_uint4(o[0], o[1], o[2], o[3]);
        *(uint4*)(dst + e * 16 + 8) = make_uint4(o[4], o[5], o[6], o[7]);
    }
}

// Deterministic split-K reduction: out[b][j] = sum_z P[z][b][j] + bias[j].
template <int N, int KSPLIT>
__global__ void reduce_out(const float* __restrict__ P, const float* __restrict__ bias,
                           float* __restrict__ out) {
    const size_t idx = ((size_t)blockIdx.x * 256 + threadIdx.x) * 4;   // float4 granule
    const int j = (int)(idx % N);                                       // N % 4 == 0
    float4 s = *(const float4*)(P + idx);
    #pragma unroll
    for (int z = 1; z < KSPLIT; ++z) {
        const float4 v = *(const float4*)(P + (size_t)z * BATCH * N + idx);
        s.x += v.x; s.y += v.y; s.z += v.z; s.w += v.w;
    }
    const float4 bv = *(const float4*)(bias + j);
    s.x += bv.x; s.y += bv.y; s.z += bv.z; s.w += bv.w;
    *(float4*)(out + idx) = s;
}

// ------------- main bf16 GEMM: 256x256 tile, 8 waves, 4-phase + counted lgkmcnt -------------
// v14 == v9/v12 verbatim -- the session's verified optimum (layer-2 514 us, MfmaUtil 47.7%,
// WRITE_SIZE 66 MB, 0 bank conflicts; end-to-end 1160 us, reproduced twice).
// STRUCTURAL CEILING (measured, rounds 8-13): (a) any live state beyond acc[8][4]+124 arch
// regs spills to scratch (v8/v11) or degrades to flat_load via hoisted generic pointers
// (v10); (b) intra-block occupancy doesn't help -- waves are s_barrier-lockstepped (v13:
// occupancy 23.5->44, MfmaUtil 47.7->37); (c) 128 KB LDS pins 1 block/CU, and smaller
// tiles/BK worsen the MFMA-per-barrier ratio (v5: 33%). Schedule is at m201 granularity
// (16 MFMA/phase, counted lgkm + vmcnt(6), swizzle-clean); non-GEMM passes are at BW floor.
template <int K, int N, int KSPLIT>
__global__ __launch_bounds__(512, 2)
void kan_gemm(const unsigned short* __restrict__ A,
              const unsigned short* __restrict__ B,
              float* __restrict__ P)
{
    __shared__ unsigned short As[2 * 2 * 128 * 64];   // 64 KB
    __shared__ unsigned short Bs[2 * 2 * 128 * 64];   // 64 KB

    const int tid  = threadIdx.x;
    const int lane = tid & 63;
    const int wave = tid >> 6;          // 0..7
    const int wm   = wave >> 2;         // 0..1: wave row -> 128 batch rows
    const int wn   = wave & 3;          // 0..3: wave col -> 64 out cols
    const int fr   = lane & 15;
    const int fq   = lane >> 4;

    // 2-D XCD chunk swizzle over 256-tiles (round-4 verified).
    constexpr int NBX = BATCH / 256;
    constexpr int NBY = N / 256;
    constexpr int NWG = NBX * NBY;
    constexpr int S   = NWG / 8;
    constexpr int CC  = (NBY >= 8) ? 8 : NBY;
    constexpr int CR  = S / CC;
    constexpr int GR  = NBX / CR;
    const int wg  = blockIdx.y * NBX + blockIdx.x;
    const int xc  = wg & 7;
    const int ci  = wg >> 3;
    const int row0 = ((xc % GR) * CR + ci % CR) * 256;
    const int col0 = ((xc / GR) * CC + ci / CR) * 256;

    constexpr int KCH = K / KSPLIT;
    const int kt0 = ((int)blockIdx.z * KCH) >> 6;
    const int nt  = KCH >> 6;

    const int srow = lane >> 3;                   // 0..7 within the wave's 8-row stripe
    const int scol = ((lane & 7) ^ srow) * 16;    // pre-swizzled global 16B chunk (bytes)

    auto STA = [&](int b, int h, int kt) {
        #pragma unroll
        for (int r2 = 0; r2 < 2; ++r2)
            gload_lds16((const char*)A +
                        ((size_t)(row0 + h * 128 + r2 * 64 + wave * 8 + srow) * K + (size_t)kt * 64) * 2 + scol,
                        (char*)&As[((b * 2 + h) * 128 + r2 * 64 + wave * 8) * 64]);
    };
    auto STB = [&](int b, int h, int kt) {
        #pragma unroll
        for (int r2 = 0; r2 < 2; ++r2)
            gload_lds16((const char*)B +
                        ((size_t)(col0 + h * 128 + r2 * 64 + wave * 8 + srow) * K + (size_t)kt * 64) * 2 + scol,
                        (char*)&Bs[((b * 2 + h) * 128 + r2 * 64 + wave * 8) * 64]);
    };
    auto LDA = [&](int b, int m, int ks) -> bf16x8 {
        return *(const bf16x8*)&As[((b * 2 + wm) * 128 + m * 16 + fr) * 64 +
                                   (((ks * 4 + fq) ^ (fr & 7)) << 3)];
    };
    auto LDB = [&](int b, int n, int ks) -> bf16x8 {
        return *(const bf16x8*)&Bs[((b * 2 + (wn >> 1)) * 128 + (wn & 1) * 64 + n * 16 + fr) * 64 +
                                   (((ks * 4 + fq) ^ (fr & 7)) << 3)];
    };

    f32x4 acc[8][4] = {};

    // Prologue: tile0 all 4 halves + tile1 {B0,A0,A1} (B1(t=1) staged in tile0's P1).
    STA(0, 0, kt0); STA(0, 1, kt0); STB(0, 0, kt0); STB(0, 1, kt0);
    STB(1, 0, kt0 + 1); STA(1, 0, kt0 + 1); STA(1, 1, kt0 + 1);
    asm volatile("s_waitcnt vmcnt(6)" ::: "memory");
    __builtin_amdgcn_s_barrier();
    __builtin_amdgcn_sched_barrier(0);

    #pragma unroll 1
    for (int t = 0; t < nt; ++t) {
        const int b  = t & 1;
        const int kt = kt0 + t;
        bf16x8 bF[8], aFa[8], aFb[8];

        // ---- P1: issue bF[8] + aFa m0-1, [pin], aFa m2-3; stage B1(t+1) -> buf^1
        #pragma unroll
        for (int n = 0; n < 4; ++n) { bF[n * 2] = LDB(b, n, 0); bF[n * 2 + 1] = LDB(b, n, 1); }
        #pragma unroll
        for (int mm = 0; mm < 2; ++mm) { aFa[mm * 2] = LDA(b, mm, 0); aFa[mm * 2 + 1] = LDA(b, mm, 1); }
        __builtin_amdgcn_sched_barrier(0);   // oldest-12 boundary (bF + aFa m0-1)
        #pragma unroll
        for (int mm = 2; mm < 4; ++mm) { aFa[mm * 2] = LDA(b, mm, 0); aFa[mm * 2 + 1] = LDA(b, mm, 1); }
        if (t + 1 < nt) STB(b ^ 1, 1, kt + 1);
        __builtin_amdgcn_sched_barrier(0);
        __builtin_amdgcn_s_barrier();
        asm volatile("s_waitcnt lgkmcnt(4)" ::: "memory");   // retire bF + aFa m0-1
        __builtin_amdgcn_sched_barrier(0);
        __builtin_amdgcn_s_setprio(1);
        #pragma unroll
        for (int ks = 0; ks < 2; ++ks)
            #pragma unroll
            for (int mm = 0; mm < 2; ++mm)
                #pragma unroll
                for (int n = 0; n < 4; ++n)
                    acc[mm][n] = __builtin_amdgcn_mfma_f32_16x16x32_bf16(
                        aFa[mm * 2 + ks], bF[n * 2 + ks], acc[mm][n], 0, 0, 0);
        __builtin_amdgcn_s_setprio(0);

        // ---- P2: issue aFb m4-5, [pin], aFb m6-7; stage B0(t+2) -> buf b
        #pragma unroll
        for (int mm = 0; mm < 2; ++mm) { aFb[mm * 2] = LDA(b, 4 + mm, 0); aFb[mm * 2 + 1] = LDA(b, 4 + mm, 1); }
        __builtin_amdgcn_sched_barrier(0);   // aFb m4-5 | m6-7 boundary
        #pragma unroll
        for (int mm = 2; mm < 4; ++mm) { aFb[mm * 2] = LDA(b, 4 + mm, 0); aFb[mm * 2 + 1] = LDA(b, 4 + mm, 1); }
        if (t + 2 < nt) STB(b, 0, kt + 2);
        __builtin_amdgcn_sched_barrier(0);
        __builtin_amdgcn_s_barrier();
        asm volatile("s_waitcnt lgkmcnt(8)" ::: "memory");   // retire aFa m2-3
        __builtin_amdgcn_sched_barrier(0);
        __builtin_amdgcn_s_setprio(1);
        #pragma unroll
        for (int ks = 0; ks < 2; ++ks)
            #pragma unroll
            for (int mm = 0; mm < 2; ++mm)
                #pragma unroll
                for (int n = 0; n < 4; ++n)
                    acc[2 + mm][n] = __builtin_amdgcn_mfma_f32_16x16x32_bf16(
                        aFa[(2 + mm) * 2 + ks], bF[n * 2 + ks], acc[2 + mm][n], 0, 0, 0);
        __builtin_amdgcn_s_setprio(0);

        // ---- P3: stage A0(t+2) -> buf b; MFMA m4-5 (aFb m4-5 retire via lgkmcnt(4))
        if (t + 2 < nt) STA(b, 0, kt + 2);
        __builtin_amdgcn_sched_barrier(0);
        __builtin_amdgcn_s_barrier();
        asm volatile("s_waitcnt lgkmcnt(4)" ::: "memory");   // retire aFb m4-5
        __builtin_amdgcn_sched_barrier(0);
        __builtin_amdgcn_s_setprio(1);
        #pragma unroll
        for (int ks = 0; ks < 2; ++ks)
            #pragma unroll
            for (int mm = 0; mm < 2; ++mm)
                #pragma unroll
                for (int n = 0; n < 4; ++n)
                    acc[4 + mm][n] = __builtin_amdgcn_mfma_f32_16x16x32_bf16(
                        aFb[mm * 2 + ks], bF[n * 2 + ks], acc[4 + mm][n], 0, 0, 0);
        __builtin_amdgcn_s_setprio(0);

        // ---- P4: stage A1(t+2); counted vmcnt certifies t+1; MFMA m6-7
        if (t + 2 < nt) {
            STA(b, 1, kt + 2);
            asm volatile("s_waitcnt vmcnt(6)" ::: "memory");
        } else {
            asm volatile("s_waitcnt vmcnt(0)" ::: "memory");
        }
        __builtin_amdgcn_sched_barrier(0);
        __builtin_amdgcn_s_barrier();
        asm volatile("s_waitcnt lgkmcnt(0)" ::: "memory");   // retire aFb m6-7
        __builtin_amdgcn_sched_barrier(0);
        __builtin_amdgcn_s_setprio(1);
        #pragma unroll
        for (int ks = 0; ks < 2; ++ks)
            #pragma unroll
            for (int mm = 0; mm < 2; ++mm)
                #pragma unroll
                for (int n = 0; n < 4; ++n)
                    acc[6 + mm][n] = __builtin_amdgcn_mfma_f32_16x16x32_bf16(
                        aFb[(2 + mm) * 2 + ks], bF[n * 2 + ks], acc[6 + mm][n], 0, 0, 0);
        __builtin_amdgcn_s_setprio(0);
        __builtin_amdgcn_sched_barrier(0);
        __builtin_amdgcn_s_barrier();       // P4 close: protects next tile's P1 stage
    }

    // Epilogue: split-K partial plane. C/D layout: col = lane&15, row = (lane>>4)*4+reg.
    float* Pz = P + (size_t)blockIdx.z * BATCH * N;
    #pragma unroll
    for (int m = 0; m < 8; ++m) {
        const int gr0 = row0 + wm * 128 + m * 16 + fq * 4;
        #pragma unroll
        for (int n = 0; n < 4; ++n) {
            const int gc = col0 + wn * 64 + n * 16 + fr;
            #pragma unroll
            for (int q = 0; q < 4; ++q)
                Pz[(size_t)(gr0 + q) * N + gc] = acc[m][n][q];
        }
    }
}

extern "C" void kernel_launch(void* const* d_in, const int* in_sizes, int n_in,
                              void* d_out, int out_size, void* d_ws, size_t ws_size,
                              hipStream_t stream) {
    (void)in_sizes; (void)n_in; (void)ws_size; (void)out_size;
    const float* x  = (const float*)d_in[0];   // [4096][768]
    const float* C1 = (const float*)d_in[1];   // [2][2048][768][8]
    const float* b1 = (const float*)d_in[2];   // [2048]
    const float* C2 = (const float*)d_in[3];   // [2][2048][2048][8]
    const float* b2 = (const float*)d_in[4];   // [2048]
    const float* C3 = (const float*)d_in[5];   // [2][512][2048][8]
    const float* b3 = (const float*)d_in[6];   // [512]
    float* out = (float*)d_out;                // [4096][512]

    // Workspace layout, lifetime-aliased (proven). Peak 554 MB.
    char* ws = (char*)d_ws;
    const size_t SZ_A1  = (size_t)4096 * 12288 * 2;      // 100,663,296
    const size_t SZ_B1  = (size_t)2048 * 12288 * 2;      //  50,331,648
    const size_t SZ_P12 = (size_t)2 * 4096 * 2048 * 4;   //  67,108,864
    const size_t SZ_A2  = (size_t)4096 * 32768 * 2;      // 268,435,456
    unsigned short* A1 = (unsigned short*)(ws);
    unsigned short* B1 = (unsigned short*)(ws + SZ_A1);
    float*          P1 = (float*)(ws + SZ_A1 + SZ_B1);
    unsigned short* A2 = (unsigned short*)(ws + SZ_A1 + SZ_B1 + SZ_P12);
    unsigned short* B2 = (unsigned short*)(ws);                           // aliases dead A1+B1
    float*          P2 = (float*)(ws + SZ_A1 + SZ_B1 + SZ_P12 + SZ_A2);
    unsigned short* A3 = (unsigned short*)(ws);                           // aliases dead B2/P1
    unsigned short* B3 = (unsigned short*)(ws + SZ_A2);
    float*          P3 = (float*)(ws + SZ_A2 + (size_t)512 * 32768 * 2);

    // ---- layer 1: (4096 x 12288) x (2048 x 12288)^T, split-K x2 -> feats -> A2
    conv_C<768, 2048><<<dim3(768 / 256, 2048), 256, 0, stream>>>(C1, B1);
    feats_x_kernel<<<dim3((4096 * 768) / 256), 256, 0, stream>>>(x, A1);
    kan_gemm<12288, 2048, 2><<<dim3(16, 8, 2), 512, 0, stream>>>(A1, B1, P1);
    reduce_feats<2048, 2><<<dim3((BATCH * 2048 / 4) / 256), 256, 0, stream>>>(P1, b1, A2);

    // ---- layer 2: (4096 x 32768) x (2048 x 32768)^T, split-K x2 -> feats -> A3
    conv_C<2048, 2048><<<dim3(2048 / 256, 2048), 256, 0, stream>>>(C2, B2);
    kan_gemm<32768, 2048, 2><<<dim3(16, 8, 2), 512, 0, stream>>>(A2, B2, P2);
    reduce_feats<2048, 2><<<dim3((BATCH * 2048 / 4) / 256), 256, 0, stream>>>(P2, b2, A3);

    // ---- layer 3: (4096 x 32768) x (512 x 32768)^T, split-K x8, deterministic reduce
    conv_C<2048, 512><<<dim3(2048 / 256, 512), 256, 0, stream>>>(C3, B3);
    kan_gemm<32768, 512, 8><<<dim3(16, 2, 8), 512, 0, stream>>>(A3, B3, P3);
    reduce_out<512, 8><<<dim3((BATCH * 512 / 4) / 256), 256, 0, stream>>>(P3, b3, out);
}